// Round 1
// baseline (14796.144 us; speedup 1.0000x reference)
//
#include <hip/hip_runtime.h>
#include <math.h>

#define T_STEPS 512
#define B_SZ    128
#define I_SZ    256
#define H_SZ    512
#define HX_SZ   768
#define NG      2048   // 4*H packed gate-columns
#define BT      16     // batch tile
#define JT      16     // hidden-unit tile
#define STRIDE4 193    // hx LDS row stride in float4 (772 floats: 772 % 32 == 4 -> 2-way bank alias, free)

// Pack W{f,i,c,o}[HX][H] into Wpk[HX][2048] with column c = j*4 + g so one
// float4 load yields all 4 gate weights for hidden unit j at row k.
__global__ __launch_bounds__(256) void repack_kernel(
    const float* __restrict__ Wf, const float* __restrict__ bf,
    const float* __restrict__ Wi, const float* __restrict__ bi,
    const float* __restrict__ Wc, const float* __restrict__ bc,
    const float* __restrict__ Wo, const float* __restrict__ bo,
    float* __restrict__ Wpk, float* __restrict__ bpk)
{
    int e = blockIdx.x * 256 + threadIdx.x;   // e in [0, 768*2048)
    int k = e >> 11;
    int c = e & 2047;
    int j = c >> 2;
    int g = c & 3;
    const float* Wsrc = (g == 0) ? Wf : (g == 1) ? Wi : (g == 2) ? Wc : Wo;
    Wpk[e] = Wsrc[k * H_SZ + j];
    if (blockIdx.x == 0) {
        for (int cc = threadIdx.x; cc < NG; cc += 256) {
            int jj = cc >> 2, gg = cc & 3;
            const float* bsrc = (gg == 0) ? bf : (gg == 1) ? bi : (gg == 2) ? bc : bo;
            bpk[cc] = bsrc[jj];
        }
    }
}

__device__ __forceinline__ float sigmoidf(float v) {
    return 1.0f / (1.0f + __expf(-v));
}

// One LSTM timestep: out tile [16 b x 16 j], all 4 gates fused, K = 768.
// hx = [h_prev (512) ; x_t (256)] staged in LDS per b-row.
__global__ __launch_bounds__(256) void lstm_step(
    const float* __restrict__ x_t,    // [B][I]
    const float* __restrict__ h_prev, // [B][H] (ignored when t0 != 0)
    float* __restrict__ Cst,          // [B][H] cell state (in/out)
    const float* __restrict__ Wpk,    // [768][2048]
    const float* __restrict__ bpk,    // [2048]
    float* __restrict__ h_out,        // [B][H]  (== out + t*B*H)
    int t0)
{
    __shared__ float4 hx4[BT * STRIDE4];

    const int tid  = threadIdx.x;
    const int bt   = blockIdx.x & 7;    // 8 b-tiles
    const int jt   = blockIdx.x >> 3;   // 32 j-tiles
    const int b0   = bt * BT;
    const int j0   = jt * JT;
    const int lane = tid & 63;
    const int wv   = tid >> 6;

    // ---- stage hx tile: 16 rows x 192 float4 (768 floats) ----
    for (int bl = wv; bl < BT; bl += 4) {
        const int b = b0 + bl;
        for (int kq = lane; kq < 192; kq += 64) {
            float4 v;
            if (kq < 128) {  // h part (k = kq*4 < 512)
                if (t0) v = make_float4(0.f, 0.f, 0.f, 0.f);
                else    v = ((const float4*)h_prev)[b * 128 + kq];
            } else {         // x part
                v = ((const float4*)x_t)[b * 64 + (kq - 128)];
            }
            hx4[bl * STRIDE4 + kq] = v;
        }
    }
    __syncthreads();

    // ---- GEMM: each thread computes (b, j) with 4 gate dots, K=768 ----
    const int bl = tid & 15;
    const int jl = tid >> 4;
    const int b  = b0 + bl;
    const int j  = j0 + jl;

    float accf = 0.f, acci = 0.f, accc = 0.f, acco = 0.f;
    const float4* __restrict__ W4 = (const float4*)Wpk;  // row = 512 float4

    #pragma unroll 4
    for (int kq = 0; kq < 192; ++kq) {
        const float4 a  = hx4[bl * STRIDE4 + kq];
        const int    kk = kq << 2;
        const float4 w0 = W4[(size_t)(kk + 0) * 512 + j];
        const float4 w1 = W4[(size_t)(kk + 1) * 512 + j];
        const float4 w2 = W4[(size_t)(kk + 2) * 512 + j];
        const float4 w3 = W4[(size_t)(kk + 3) * 512 + j];
        accf += a.x * w0.x; acci += a.x * w0.y; accc += a.x * w0.z; acco += a.x * w0.w;
        accf += a.y * w1.x; acci += a.y * w1.y; accc += a.y * w1.z; acco += a.y * w1.w;
        accf += a.z * w2.x; acci += a.z * w2.y; accc += a.z * w2.z; acco += a.z * w2.w;
        accf += a.w * w3.x; acci += a.w * w3.y; accc += a.w * w3.z; acco += a.w * w3.w;
    }

    // ---- pointwise gates ----
    const float4 bias = ((const float4*)bpk)[j];
    const float f  = sigmoidf(accf + bias.x);
    const float i_ = sigmoidf(acci + bias.y);
    const float cb = tanhf(accc + bias.z);
    const float o  = sigmoidf(acco + bias.w);

    const int idx = b * H_SZ + j;
    const float Cold = t0 ? 0.f : Cst[idx];
    const float Cn = f * Cold + i_ * cb;
    Cst[idx]   = Cn;
    h_out[idx] = o * tanhf(Cn);
}

extern "C" void kernel_launch(void* const* d_in, const int* in_sizes, int n_in,
                              void* d_out, int out_size, void* d_ws, size_t ws_size,
                              hipStream_t stream)
{
    const float* x  = (const float*)d_in[0];
    const float* Wf = (const float*)d_in[1];
    const float* bf = (const float*)d_in[2];
    const float* Wi = (const float*)d_in[3];
    const float* bi = (const float*)d_in[4];
    const float* Wc = (const float*)d_in[5];
    const float* bc = (const float*)d_in[6];
    const float* Wo = (const float*)d_in[7];
    const float* bo = (const float*)d_in[8];
    float* out = (float*)d_out;

    float* Wpk = (float*)d_ws;                 // 768*2048 floats
    float* bpk = Wpk + (size_t)HX_SZ * NG;     // 2048 floats
    float* Cst = bpk + NG;                     // 128*512 floats

    repack_kernel<<<(HX_SZ * NG) / 256, 256, 0, stream>>>(
        Wf, bf, Wi, bi, Wc, bc, Wo, bo, Wpk, bpk);

    for (int t = 0; t < T_STEPS; ++t) {
        const float* x_t    = x + (size_t)t * B_SZ * I_SZ;
        const float* h_prev = (t == 0) ? out : out + (size_t)(t - 1) * B_SZ * H_SZ;
        float*       h_out  = out + (size_t)t * B_SZ * H_SZ;
        lstm_step<<<256, 256, 0, stream>>>(x_t, h_prev, Cst, Wpk, bpk, h_out,
                                           (t == 0) ? 1 : 0);
    }
}

// Round 3
// 6388.782 us; speedup vs baseline: 2.3160x; 2.3160x over previous
//
#include <hip/hip_runtime.h>
#include <math.h>

#define T_STEPS 512
#define B_SZ    128
#define I_SZ    256
#define H_SZ    512
#define HX_SZ   768
#define NG      2048      // 4*H gate-columns, packed n = jh*4 + gate
#define KB_H    16        // k-instructions covering h part (512/32)
#define KB_TOT  24        // total k-instructions (768/32)
#define W_ELEMS (HX_SZ * NG)   // 1,572,864 per pack

typedef __attribute__((ext_vector_type(8))) short bf16x8;   // MFMA A/B frag (4 VGPRs)
typedef __attribute__((ext_vector_type(4))) float f32x4;    // MFMA C/D frag

__device__ __forceinline__ unsigned short f2bf_rne(float f) {
    unsigned u = __builtin_bit_cast(unsigned, f);
    unsigned r = u + 0x7fffu + ((u >> 16) & 1u);
    return (unsigned short)(r >> 16);
}
__device__ __forceinline__ float bf2f(unsigned short h) {
    unsigned u = ((unsigned)h) << 16;
    return __builtin_bit_cast(float, u);
}

// ---- Pack W{f,i,c,o}[768][512] into MFMA-B-fragment order, bf16 hi + lo ----
// dst flat index: id = ((ng*KB_TOT + kb)*64 + lane)*8 + j
//   n = ng*16 + (lane&15); k = kb*32 + (lane>>4)*8 + j;  element = W[k][n]
//   gate-col n -> (jh = n>>2, g = n&3)
__global__ __launch_bounds__(256) void repack_frag(
    const float* __restrict__ Wf, const float* __restrict__ Wi,
    const float* __restrict__ Wc, const float* __restrict__ Wo,
    unsigned short* __restrict__ Whi, unsigned short* __restrict__ Wlo)
{
    int id = blockIdx.x * 256 + threadIdx.x;           // [0, 1572864)
    int j    = id & 7;
    int lane = (id >> 3) & 63;
    int fkb  = (id >> 9);
    int kb   = fkb % KB_TOT;
    int ng   = fkb / KB_TOT;
    int n = ng * 16 + (lane & 15);
    int k = kb * 32 + (lane >> 4) * 8 + j;
    int g  = n & 3;
    int jh = n >> 2;
    const float* Ws = (g == 0) ? Wf : (g == 1) ? Wi : (g == 2) ? Wc : Wo;
    float w = Ws[k * H_SZ + jh];
    unsigned short wh = f2bf_rne(w);
    unsigned short wl = f2bf_rne(w - bf2f(wh));
    Whi[id] = wh;
    Wlo[id] = wl;
}

__global__ __launch_bounds__(256) void pack_bias(
    const float* __restrict__ bf, const float* __restrict__ bi,
    const float* __restrict__ bc, const float* __restrict__ bo,
    float* __restrict__ bpk)
{
    int c = blockIdx.x * 256 + threadIdx.x;   // [0, 2048)
    int jh = c >> 2, g = c & 3;
    const float* bs = (g == 0) ? bf : (g == 1) ? bi : (g == 2) ? bc : bo;
    bpk[c] = bs[jh];
}

// ---- One LSTM timestep via bf16 MFMA with hi/lo compensation ----
// Grid: 256 WGs x 256 thr. WG w: xcd=w&7 -> n-region (L2-resident weight slice),
// q=w>>3: bt=q&7 (16-row b-tile), ngg = xcd*4 + (q>>3) in [0,32) (64-col group).
// Wave v handles ng = ngg*4 + v (16 cols), full K.
__global__ __launch_bounds__(256) void lstm_step(
    const float* __restrict__ x_t,             // [B][I] fp32
    const unsigned short* __restrict__ h_hi,   // [B][H] bf16 hi (prev step)
    const unsigned short* __restrict__ h_lo,   // [B][H] bf16 lo
    const unsigned short* __restrict__ Whi,    // frag-packed bf16
    const unsigned short* __restrict__ Wlo,
    const float* __restrict__ bpk,             // [2048] packed bias
    float* __restrict__ Cst,                   // [B][H] cell state
    float* __restrict__ h_out,                 // fp32 out + t*B*H
    unsigned short* __restrict__ hhi_o,        // bf16 hi for next step
    unsigned short* __restrict__ hlo_o,        // bf16 lo for next step
    int t0)
{
    __shared__ float preact[16][64];

    const int tid  = threadIdx.x;
    const int lane = tid & 63;
    const int wv   = tid >> 6;
    const int w    = blockIdx.x;
    const int xcd  = w & 7;
    const int q    = w >> 3;
    const int bt   = q & 7;
    const int ngg  = xcd * 4 + (q >> 3);
    const int ng   = ngg * 4 + wv;
    const int b0   = bt * 16;

    const int mrow = lane & 15;   // A row / D col index
    const int quad = lane >> 4;
    const int b    = b0 + mrow;

    f32x4 acc = {0.f, 0.f, 0.f, 0.f};

    const bf16x8* __restrict__ Wh8 = (const bf16x8*)Whi;
    const bf16x8* __restrict__ Wl8 = (const bf16x8*)Wlo;
    const int wbase = ng * KB_TOT * 64 + lane;

    // ---- h part: k in [0,512), A = h_prev (pre-split bf16 hi/lo) ----
    if (!t0) {
        #pragma unroll
        for (int kb = 0; kb < KB_H; ++kb) {
            const int k = kb * 32 + quad * 8;
            bf16x8 ah = *(const bf16x8*)(h_hi + b * H_SZ + k);
            bf16x8 al = *(const bf16x8*)(h_lo + b * H_SZ + k);
            bf16x8 wh = Wh8[wbase + kb * 64];
            bf16x8 wl = Wl8[wbase + kb * 64];
            acc = __builtin_amdgcn_mfma_f32_16x16x32_bf16(ah, wh, acc, 0, 0, 0);
            acc = __builtin_amdgcn_mfma_f32_16x16x32_bf16(al, wh, acc, 0, 0, 0);
            acc = __builtin_amdgcn_mfma_f32_16x16x32_bf16(ah, wl, acc, 0, 0, 0);
        }
    }

    // ---- x part: k in [512,768), convert fp32 x -> bf16 hi/lo in-register ----
    #pragma unroll
    for (int kb = KB_H; kb < KB_TOT; ++kb) {
        const int kx = kb * 32 + quad * 8 - H_SZ;
        const float* xp = x_t + b * I_SZ + kx;
        f32x4 x0 = *(const f32x4*)xp;
        f32x4 x1 = *(const f32x4*)(xp + 4);
        float xs[8] = {x0[0], x0[1], x0[2], x0[3], x1[0], x1[1], x1[2], x1[3]};
        bf16x8 xh, xl;
        #pragma unroll
        for (int j = 0; j < 8; ++j) {
            unsigned short hbits = f2bf_rne(xs[j]);
            xh[j] = (short)hbits;
            xl[j] = (short)f2bf_rne(xs[j] - bf2f(hbits));
        }
        bf16x8 wh = Wh8[wbase + kb * 64];
        bf16x8 wl = Wl8[wbase + kb * 64];
        acc = __builtin_amdgcn_mfma_f32_16x16x32_bf16(xh, wh, acc, 0, 0, 0);
        acc = __builtin_amdgcn_mfma_f32_16x16x32_bf16(xl, wh, acc, 0, 0, 0);
        acc = __builtin_amdgcn_mfma_f32_16x16x32_bf16(xh, wl, acc, 0, 0, 0);
    }

    // ---- stage pre-activations to LDS (D layout: col=lane&15, row=quad*4+r) ----
    #pragma unroll
    for (int r = 0; r < 4; ++r)
        preact[quad * 4 + r][wv * 16 + mrow] = acc[r];
    __syncthreads();

    // ---- pointwise: thread -> (b_local, hidden_local); WG covers 16b x 16 hidden ----
    const int bl = tid >> 4;
    const int jl = tid & 15;
    const int jh = ngg * 16 + jl;
    const int bg = b0 + bl;

    f32x4 bias = ((const f32x4*)bpk)[ngg * 16 + jl];
    float pf = preact[bl][jl * 4 + 0] + bias[0];
    float pi = preact[bl][jl * 4 + 1] + bias[1];
    float pc = preact[bl][jl * 4 + 2] + bias[2];
    float po = preact[bl][jl * 4 + 3] + bias[3];

    float fg = 1.f / (1.f + __expf(-pf));
    float ig = 1.f / (1.f + __expf(-pi));
    float cb = tanhf(pc);
    float og = 1.f / (1.f + __expf(-po));

    const int idx = bg * H_SZ + jh;
    float Cold = t0 ? 0.f : Cst[idx];
    float Cn = fg * Cold + ig * cb;
    float hn = og * tanhf(Cn);

    Cst[idx]   = Cn;
    h_out[idx] = hn;
    unsigned short hh = f2bf_rne(hn);
    hhi_o[idx] = hh;
    hlo_o[idx] = f2bf_rne(hn - bf2f(hh));
}

extern "C" void kernel_launch(void* const* d_in, const int* in_sizes, int n_in,
                              void* d_out, int out_size, void* d_ws, size_t ws_size,
                              hipStream_t stream)
{
    const float* x  = (const float*)d_in[0];
    const float* Wf = (const float*)d_in[1];
    const float* bf = (const float*)d_in[2];
    const float* Wi = (const float*)d_in[3];
    const float* bi = (const float*)d_in[4];
    const float* Wc = (const float*)d_in[5];
    const float* bc = (const float*)d_in[6];
    const float* Wo = (const float*)d_in[7];
    const float* bo = (const float*)d_in[8];
    float* out = (float*)d_out;

    // ---- workspace layout (all 16B aligned) ----
    unsigned short* Whi = (unsigned short*)d_ws;          // 1,572,864 shorts
    unsigned short* Wlo = Whi + W_ELEMS;                  // 1,572,864 shorts
    float* bpk = (float*)(Wlo + W_ELEMS);                 // 2048 floats
    float* Cst = bpk + NG;                                // 65536 floats
    unsigned short* hb = (unsigned short*)(Cst + B_SZ * H_SZ);
    unsigned short* hhiP[2] = { hb,                hb + 1 * 65536 };
    unsigned short* hloP[2] = { hb + 2 * 65536,    hb + 3 * 65536 };

    repack_frag<<<W_ELEMS / 256, 256, 0, stream>>>(Wf, Wi, Wc, Wo, Whi, Wlo);
    pack_bias<<<NG / 256, 256, 0, stream>>>(bf, bi, bc, bo, bpk);

    for (int t = 0; t < T_STEPS; ++t) {
        const int pw = t & 1;        // write parity
        const int pr = pw ^ 1;       // read parity
        lstm_step<<<256, 256, 0, stream>>>(
            x + (size_t)t * B_SZ * I_SZ,
            hhiP[pr], hloP[pr],
            Whi, Wlo, bpk, Cst,
            out + (size_t)t * B_SZ * H_SZ,
            hhiP[pw], hloP[pw],
            (t == 0) ? 1 : 0);
    }
}